// Round 1
// baseline (65.655 us; speedup 1.0000x reference)
//
#include <hip/hip_runtime.h>

// Problem constants (match reference)
#define BB   16384
#define SS   20
#define DD   128
#define VV   12
#define NBB  2          // batch rows per 256-thread block
#define ROWW (DD + 8)   // +4 zero pad each side for dilation-4 taps
#define EPSV 1e-5f

__global__ __launch_bounds__(256, 4) void fused_mdt_kernel(
    const int*   __restrict__ tokens,   // [B,S]
    const float* __restrict__ emb,      // [V,D]
    const float* __restrict__ pre_w,    // [S]
    const float* __restrict__ w0, const float* __restrict__ b0,  // [S,1,3],[S]
    const float* __restrict__ w1, const float* __restrict__ b1,
    const float* __restrict__ w2, const float* __restrict__ b2,
    const float* __restrict__ gate_w,   // [S,S] (t,s)
    const float* __restrict__ gate_b,   // [S]
    const float* __restrict__ post_w,   // [S]
    const float* __restrict__ logit_w,  // [1,S,1] -> flat [S]
    float*       __restrict__ out)      // [B,1,D] -> flat [B*D]
{
    __shared__ float s_emb[VV * DD];            // 6 KB
    __shared__ float s_xn[NBB][SS][ROWW];       // ~21.8 KB

    const int tid = threadIdx.x;
    const int bl  = tid >> 7;          // 0..1  : which batch row in block
    const int d   = tid & 127;         // 0..127: embed index
    const int b   = blockIdx.x * NBB + bl;

    // ---- phase 0: stage emb into LDS, zero conv pads ----
    {
        const float4* e4 = reinterpret_cast<const float4*>(emb);
        float4*       s4 = reinterpret_cast<float4*>(s_emb);
        for (int i = tid; i < VV * DD / 4; i += 256) s4[i] = e4[i];
        // pad slots: NBB*SS*8 = 320 entries
        for (int p = tid; p < NBB * SS * 8; p += 256) {
            int bb  = p / (SS * 8);
            int rem = p % (SS * 8);
            int s = rem >> 3, k = rem & 7;
            int j = (k < 4) ? k : (DD + k);    // 0..3 | 132..135
            s_xn[bb][s][j] = 0.f;
        }
    }

    // tokens for this thread's batch row: 5x int4 (80 B, 16B-aligned)
    int tok[SS];
    {
        const int4* t4 = reinterpret_cast<const int4*>(tokens + b * SS);
        #pragma unroll
        for (int i = 0; i < 5; ++i) {
            int4 v = t4[i];
            tok[4*i+0] = v.x; tok[4*i+1] = v.y;
            tok[4*i+2] = v.z; tok[4*i+3] = v.w;
        }
    }

    __syncthreads();

    // ---- phase 1: x = emb[tok], ms over S, residual dot acc1 ----
    float xv[SS];
    float ms = 0.f, acc1 = 0.f;
    #pragma unroll
    for (int s = 0; s < SS; ++s) {
        float x = s_emb[tok[s] * DD + d];
        xv[s] = x;
        ms   = fmaf(x, x, ms);
        acc1 = fmaf(x, logit_w[s], acc1);   // sum_s x[s]*logit_w[s]
    }
    const float r = rsqrtf(ms * (1.f / SS) + EPSV);

    // x_norm = x * rsqrt(ms) * pre_w[s]; keep in regs AND stage in LDS
    #pragma unroll
    for (int s = 0; s < SS; ++s) {
        float xn = xv[s] * (r * pre_w[s]);
        xv[s] = xn;
        s_xn[bl][s][4 + d] = xn;
    }

    __syncthreads();

    // ---- phase 2: fused 3-dilation depthwise conv along d ----
    float xd[SS];
    #pragma unroll
    for (int s = 0; s < SS; ++s) {
        const float* row = &s_xn[bl][s][4 + d];
        const float  c   = xv[s];              // center tap from regs
        float acc = b0[s] + b1[s] + b2[s];
        acc = fmaf(w0[s*3+0], row[-1], acc);
        acc = fmaf(w0[s*3+1], c,       acc);
        acc = fmaf(w0[s*3+2], row[ 1], acc);
        acc = fmaf(w1[s*3+0], row[-2], acc);
        acc = fmaf(w1[s*3+1], c,       acc);
        acc = fmaf(w1[s*3+2], row[ 2], acc);
        acc = fmaf(w2[s*3+0], row[-4], acc);
        acc = fmaf(w2[s*3+1], c,       acc);
        acc = fmaf(w2[s*3+2], row[ 4], acc);
        xd[s] = acc;
    }

    // ---- phase 3: gate matvec (20x20) + SiLU, post-RMSNorm, output ----
    float ms2 = 0.f, acc2 = 0.f;
    #pragma unroll
    for (int t = 0; t < SS; ++t) {
        float g = gate_b[t];
        #pragma unroll
        for (int s = 0; s < SS; ++s)
            g = fmaf(xv[s], gate_w[t * SS + s], g);
        // silu(g) = g * sigmoid(g)
        float sg = __builtin_amdgcn_rcpf(1.f + __expf(-g));
        float h  = xd[t] * (g * sg);
        ms2  = fmaf(h, h, ms2);
        acc2 = fmaf(h, post_w[t] * logit_w[t], acc2);
    }
    const float r2 = rsqrtf(ms2 * (1.f / SS) + EPSV);

    out[b * DD + d] = acc1 + r2 * acc2;
}

extern "C" void kernel_launch(void* const* d_in, const int* in_sizes, int n_in,
                              void* d_out, int out_size, void* d_ws, size_t ws_size,
                              hipStream_t stream) {
    const int*   tokens  = (const int*)  d_in[0];
    // d_in[1] = number_log — unused by the reference
    const float* emb     = (const float*)d_in[2];
    const float* pre_w   = (const float*)d_in[3];
    const float* w0      = (const float*)d_in[4];
    const float* b0      = (const float*)d_in[5];
    const float* w1      = (const float*)d_in[6];
    const float* b1      = (const float*)d_in[7];
    const float* w2      = (const float*)d_in[8];
    const float* b2      = (const float*)d_in[9];
    const float* gate_w  = (const float*)d_in[10];
    const float* gate_b  = (const float*)d_in[11];
    const float* post_w  = (const float*)d_in[12];
    const float* logit_w = (const float*)d_in[13];
    float*       out     = (float*)d_out;

    dim3 grid(BB / NBB);   // 8192 blocks
    dim3 block(256);
    hipLaunchKernelGGL(fused_mdt_kernel, grid, block, 0, stream,
                       tokens, emb, pre_w, w0, b0, w1, b1, w2, b2,
                       gate_w, gate_b, post_w, logit_w, out);
}